// Round 4
// baseline (129.820 us; speedup 1.0000x reference)
//
#include <hip/hip_runtime.h>
#include <hip/hip_bf16.h>

#define NB 16
#define NQ 128
#define NK 512
#define DIN 256   // QS == KS == 256
#define NH 128
#define NDV 256

#define CSC 2.8853900817779268f   // 2*log2(e): tanh(x) = 1 - 2/(1 + 2^(CSC*x))

// Projection v8: v7's all-LDS inner loop + occupancy fix. v7 steady (~37us)
// ran 192 active blocks on 256 CUs (<1 block/CU, ~1 wave/SIMD) -> LDS
// latency exposed. v8: 16-row tiles -> grid 128+512 (~384 active,
// ~1.5 blocks/CU, 6 waves/CU), LDS 48KB (Xl 16KB + Wl 32KB) -> 3 blocks/CU
// cap. Thread = 2 rows x 4 h, acc[2], 2048 fma. W chunk register-prefetched
// (issue next chunk's global loads BEFORE compute, ds_write after barrier).
// Outputs EXPONENTIALS: EQ = 2^(CSC*qproj), EKT = 2^(CSC*kproj) transposed;
// score kernel then needs 1 trans op per (q,k,h) instead of 2.
// K-path blocks fully beyond valid_len exit immediately (never read).
__global__ __launch_bounds__(256) void proj_both_kernel(
    const float* __restrict__ Q, const float* __restrict__ K,
    const float* __restrict__ Wq, const float* __restrict__ Wk,
    const int* __restrict__ vlen,
    float* __restrict__ EQ, float* __restrict__ EKT)
{
    __shared__ float Xl[16 * DIN];   // 16KB; reused as transpose tile (10KB) for K path
    __shared__ float Wl[64 * NH];    // 32KB; d-chunk of W
    const int tid = threadIdx.x;
    int blk = blockIdx.x;
    const float* X; const float* W;
    int b, r0, isq;
    if (blk < 128) { isq = 1; b = blk >> 3; r0 = (blk & 7) * 16;
                     X = Q + ((size_t)b * NQ + r0) * DIN; W = Wq; }
    else { blk -= 128; isq = 0; b = blk >> 5; r0 = (blk & 31) * 16;
           X = K + ((size_t)b * NK + r0) * DIN; W = Wk;
           int vl = vlen[b]; vl = vl < 1 ? 1 : (vl > NK ? NK : vl);
           if (r0 >= vl) return;     // block-uniform: masked-out key rows, never read
    }

    {   // stage 16 rows of X: 1024 float4, coalesced
        const float4* Xg = (const float4*)X;
        float4* Xs = (float4*)Xl;
        #pragma unroll
        for (int i = 0; i < 4; ++i) Xs[tid + 256 * i] = Xg[tid + 256 * i];
    }

    const int h4 = tid & 31;          // h = 4*h4
    const int rg = tid >> 5;          // rows rg*2, rg*2+1
    const float4* Wg = (const float4*)W;   // [256*128/4] float4; chunk c at c*2048
    float4* Ws4 = (float4*)Wl;

    float4 acc[2];
    #pragma unroll
    for (int r = 0; r < 2; ++r) { acc[r].x = 0.f; acc[r].y = 0.f; acc[r].z = 0.f; acc[r].w = 0.f; }

    // chunk 0: load to regs, write to LDS (first __syncthreads is inside loop)
    float4 pre[8];
    #pragma unroll
    for (int j = 0; j < 8; ++j) pre[j] = Wg[tid + 256 * j];
    #pragma unroll
    for (int j = 0; j < 8; ++j) Ws4[tid + 256 * j] = pre[j];

    for (int c = 0; c < 4; ++c) {     // 4 d-chunks of 64
        if (c < 3) {                  // issue next chunk's loads; latency hides under compute
            #pragma unroll
            for (int j = 0; j < 8; ++j) pre[j] = Wg[(c + 1) * 2048 + tid + 256 * j];
        }
        __syncthreads();              // Wl (and Xl on c==0) ready

        const float* Xc = &Xl[c * 64];
        #pragma unroll 4
        for (int dd = 0; dd < 64; dd += 4) {
            float4 w0 = *(const float4*)&Wl[(dd + 0) * NH + 4 * h4];
            float4 w1 = *(const float4*)&Wl[(dd + 1) * NH + 4 * h4];
            float4 w2 = *(const float4*)&Wl[(dd + 2) * NH + 4 * h4];
            float4 w3 = *(const float4*)&Wl[(dd + 3) * NH + 4 * h4];
            #pragma unroll
            for (int r = 0; r < 2; ++r) {
                float4 x = *(const float4*)&Xc[(rg * 2 + r) * DIN + dd];  // broadcast
                acc[r].x += x.x * w0.x + x.y * w1.x + x.z * w2.x + x.w * w3.x;
                acc[r].y += x.x * w0.y + x.y * w1.y + x.z * w2.y + x.w * w3.y;
                acc[r].z += x.x * w0.z + x.y * w1.z + x.z * w2.z + x.w * w3.z;
                acc[r].w += x.x * w0.w + x.y * w1.w + x.z * w2.w + x.w * w3.w;
            }
        }
        __syncthreads();              // all waves done reading Wl
        if (c < 3) {
            #pragma unroll
            for (int j = 0; j < 8; ++j) Ws4[tid + 256 * j] = pre[j];
        }
    }

    #pragma unroll
    for (int r = 0; r < 2; ++r) {    // scale then exponentiate: store 2^(CSC*proj)
        acc[r].x = __builtin_amdgcn_exp2f(CSC * acc[r].x);
        acc[r].y = __builtin_amdgcn_exp2f(CSC * acc[r].y);
        acc[r].z = __builtin_amdgcn_exp2f(CSC * acc[r].z);
        acc[r].w = __builtin_amdgcn_exp2f(CSC * acc[r].w);
    }

    if (isq) {
        #pragma unroll
        for (int r = 0; r < 2; ++r)
            *(float4*)&EQ[((size_t)b * NQ + r0 + rg * 2 + r) * NH + 4 * h4] = acc[r];
    } else {
        float* T = Xl;                // [128 h][20] padded (20*4B % 16 == 0)
        __syncthreads();
        #pragma unroll
        for (int r = 0; r < 2; ++r) {
            T[(4 * h4 + 0) * 20 + rg * 2 + r] = acc[r].x;
            T[(4 * h4 + 1) * 20 + rg * 2 + r] = acc[r].y;
            T[(4 * h4 + 2) * 20 + rg * 2 + r] = acc[r].z;
            T[(4 * h4 + 3) * 20 + rg * 2 + r] = acc[r].w;
        }
        __syncthreads();
        #pragma unroll
        for (int i = 0; i < 2; ++i) {
            const int idx = tid + 256 * i;        // 0..511
            const int h = idx >> 2, c4 = idx & 3; // 4 float4 per h row
            float4 v = *(const float4*)&T[h * 20 + c4 * 4];
            *(float4*)&EKT[((size_t)b * NH + h) * NK + r0 + c4 * 4] = v;
        }
    }
}

// Fused scores + masked softmax + attn@V.  Block = (b, 4 q rows), 512 thr = 8
// waves, grid 512. XCD swizzle: b = blk&15 -> all 32 blocks of batch b on one
// XCD -> EKT[b]+V[b] L2-resident (FETCH ~7MB).
// Score inner loop (the trans-pipe hot spot) is 1 trans + 2 VALU per tanh:
//   a += wvl[h] * rcp(fma(eq[h][r], ek[h][k], 1.0f))
// with eq = 2^(CSC*q), ek = 2^(CSC*k) precomputed. Saturation safe:
// rcp(inf)=0 (tanh->+1), rcp(1+0)=1 (tanh->-1).
// Masked work is skipped: threads tid>=vl skip the h-loop (whole waves branch
// out on execz); attn@V waves whose 64-k slice is >= vl skip the V loop.
// UNCHANGED from R3 (attribution: with proj fast, this surfaces in top-5 for
// steady-state counters next round).
__global__ __launch_bounds__(512) void attn_fused_kernel(
    const float* __restrict__ EQ, const float* __restrict__ EKT,
    const float* __restrict__ wv, const int* __restrict__ vlen,
    const float* __restrict__ V, float* __restrict__ OUT)
{
    __shared__ float eq4[NH * 4];        // 2KB   [h][r] packed for ds_read_b128
    __shared__ float wvl[NH];            // 0.5KB -2*wv
    __shared__ float sc[4][NK];          // 8KB   scores -> attn
    __shared__ float part[4][4][NDV];    // 16KB  [k-quarter][row][d]
    const int tid = threadIdx.x;
    const int b  = blockIdx.x & 15;      // XCD-local batch
    const int q0 = (blockIdx.x >> 4) * 4;

    {   // stage q-exponentials transposed: eq4[h*4 + r]
        const int r = tid >> 7, h = tid & 127;
        eq4[h * 4 + r] = EQ[((size_t)b * NQ + q0 + r) * NH + h];
    }
    if (tid < NH) wvl[tid] = -2.0f * wv[tid];
    __syncthreads();

    int vl = vlen[b];
    vl = vl < 1 ? 1 : (vl > NK ? NK : vl);

    // ---- scores: score'(r,k) = sum_h wvl[h]/(1 + eq[r][h]*ek[h][k])
    // (true score minus sum(wv): softmax-invariant row shift)
    {
        float a0 = 0.f, a1 = 0.f, a2 = 0.f, a3 = 0.f;
        const bool vld = (tid < vl);
        if (vld) {
            const float* kb = EKT + (size_t)b * NH * NK + tid;
            #pragma unroll 8
            for (int h = 0; h < NH; ++h) {
                float ek = kb[(size_t)h * NK];                 // coalesced, L2-hot
                float4 eq = *(const float4*)&eq4[h * 4];       // LDS broadcast b128
                float wq = wvl[h];                             // LDS broadcast b32
                a0 += wq * __builtin_amdgcn_rcpf(__builtin_fmaf(eq.x, ek, 1.0f));
                a1 += wq * __builtin_amdgcn_rcpf(__builtin_fmaf(eq.y, ek, 1.0f));
                a2 += wq * __builtin_amdgcn_rcpf(__builtin_fmaf(eq.z, ek, 1.0f));
                a3 += wq * __builtin_amdgcn_rcpf(__builtin_fmaf(eq.w, ek, 1.0f));
            }
        }
        sc[0][tid] = vld ? a0 : -1e6f;
        sc[1][tid] = vld ? a1 : -1e6f;
        sc[2][tid] = vld ? a2 : -1e6f;
        sc[3][tid] = vld ? a3 : -1e6f;
    }
    __syncthreads();

    // ---- masked softmax: wave w (0..3) owns row w
    const int w = tid >> 6, lane = tid & 63;
    if (w < 4) {
        float vals[8];
        float m = -3.0e38f;
        #pragma unroll
        for (int i = 0; i < 8; ++i) { vals[i] = sc[w][lane + 64 * i]; m = fmaxf(m, vals[i]); }
        #pragma unroll
        for (int off = 32; off; off >>= 1) m = fmaxf(m, __shfl_xor(m, off, 64));
        float s = 0.f;
        #pragma unroll
        for (int i = 0; i < 8; ++i) {
            vals[i] = __builtin_amdgcn_exp2f((vals[i] - m) * 1.4426950408889634f);
            s += vals[i];
        }
        #pragma unroll
        for (int off = 32; off; off >>= 1) s += __shfl_xor(s, off, 64);
        const float invs = 1.0f / s;   // s >= 1
        #pragma unroll
        for (int i = 0; i < 8; ++i) sc[w][lane + 64 * i] = vals[i] * invs;
    }
    __syncthreads();

    // ---- out partials: wave w covers k in [w*64, w*64+64) for ALL 4 rows
    float4 o[4];
    #pragma unroll
    for (int r = 0; r < 4; ++r) { o[r].x = 0.f; o[r].y = 0.f; o[r].z = 0.f; o[r].w = 0.f; }
    {
        const int kb0 = w * 64;
        if (kb0 < vl) {                  // wave-uniform: skip all-zero-prob slices
            const float* vb = V + (size_t)b * NK * NDV + lane * 4;
            #pragma unroll 4
            for (int kk = 0; kk < 64; ++kk) {
                const int k = kb0 + kk;
                float4 v4 = *(const float4*)(vb + (size_t)k * NDV);   // 1KB/wave coalesced
                float p0 = sc[0][k], p1 = sc[1][k], p2 = sc[2][k], p3 = sc[3][k];
                o[0].x += p0 * v4.x; o[0].y += p0 * v4.y; o[0].z += p0 * v4.z; o[0].w += p0 * v4.w;
                o[1].x += p1 * v4.x; o[1].y += p1 * v4.y; o[1].z += p1 * v4.z; o[1].w += p1 * v4.w;
                o[2].x += p2 * v4.x; o[2].y += p2 * v4.y; o[2].z += p2 * v4.z; o[2].w += p2 * v4.w;
                o[3].x += p3 * v4.x; o[3].y += p3 * v4.y; o[3].z += p3 * v4.z; o[3].w += p3 * v4.w;
            }
        }
    }
    // stage 1: waves 4-7 write partials
    if (w >= 4) {
        #pragma unroll
        for (int r = 0; r < 4; ++r) *(float4*)&part[w - 4][r][lane * 4] = o[r];
    }
    __syncthreads();
    // stage 2: waves 0-3 pair-combine and write
    if (w < 4) {
        #pragma unroll
        for (int r = 0; r < 4; ++r) {
            float4 t = *(const float4*)&part[w][r][lane * 4];
            o[r].x += t.x; o[r].y += t.y; o[r].z += t.z; o[r].w += t.w;
            *(float4*)&part[w][r][lane * 4] = o[r];
        }
    }
    __syncthreads();
    // stage 3: sum 4 k-quarter partials, store coalesced
    if (tid < 256) {
        const int r = tid >> 6, d4 = tid & 63;
        float4 s = {0.f, 0.f, 0.f, 0.f};
        #pragma unroll
        for (int p = 0; p < 4; ++p) {
            float4 q = *(const float4*)&part[p][r][d4 * 4];
            s.x += q.x; s.y += q.y; s.z += q.z; s.w += q.w;
        }
        *(float4*)&OUT[((size_t)b * NQ + q0 + r) * NDV + d4 * 4] = s;
    }
}

extern "C" void kernel_launch(void* const* d_in, const int* in_sizes, int n_in,
                              void* d_out, int out_size, void* d_ws, size_t ws_size,
                              hipStream_t stream) {
    const float* queries = (const float*)d_in[0];  // [16,128,256] f32
    const float* keys    = (const float*)d_in[1];  // [16,512,256] f32
    const float* values  = (const float*)d_in[2];  // [16,512,256] f32
    const int*   vlen    = (const int*)d_in[3];    // [16] int32
    const float* Wq      = (const float*)d_in[4];  // [256,128] f32
    const float* Wk      = (const float*)d_in[5];  // [256,128] f32
    const float* wv      = (const float*)d_in[6];  // [128] f32
    float* out           = (float*)d_out;          // [16,128,256] f32

    float* eq  = (float*)d_ws;                     // EQ  [16][128][128] = 1MB (2^(CSC*qproj))
    float* ekt = eq + (size_t)NB * NQ * NH;        // EKT [16][128][512] = 4MB (2^(CSC*kproj), transposed)

    proj_both_kernel<<<128 + 512, 256, 0, stream>>>(queries, keys, Wq, Wk, vlen, eq, ekt);
    attn_fused_kernel<<<NB * 32, 512, 0, stream>>>(eq, ekt, wv, vlen, values, out);
}

// Round 5
// 125.263 us; speedup vs baseline: 1.0364x; 1.0364x over previous
//
#include <hip/hip_runtime.h>
#include <hip/hip_bf16.h>

#define NB 16
#define NQ 128
#define NK 512
#define DIN 256   // QS == KS == 256
#define NH 128
#define NDV 256

#define CSC 2.8853900817779268f   // 2*log2(e): tanh(x) = 1 - 2/(1 + 2^(CSC*x))

// Projection v7 (reverted from v8: v8's R=2 made the inner loop LDS-bound,
// 4096 cy compute vs 4096 cy W-ds_read per block; v7's R=4 is balanced at
// 8192/8192 and measured best overall). All-LDS inner loop:
//   Xl[32][256] = 32KB staged once, Wl[64][128] = 32KB per d-chunk,
//   register-prefetched (issue next chunk's global loads BEFORE compute,
//   ds_write after the closing barrier). 64KB LDS -> 2 blocks/CU.
// Outputs EXPONENTIALS: EQ = 2^(CSC*qproj), EKT = 2^(CSC*kproj) transposed.
// K-path blocks fully beyond valid_len exit immediately (never read).
__global__ __launch_bounds__(256) void proj_both_kernel(
    const float* __restrict__ Q, const float* __restrict__ K,
    const float* __restrict__ Wq, const float* __restrict__ Wk,
    const int* __restrict__ vlen,
    float* __restrict__ EQ, float* __restrict__ EKT)
{
    __shared__ float Xl[32 * DIN];   // 32KB; reused as transpose tile for K path
    __shared__ float Wl[64 * NH];    // 32KB; d-chunk of W
    const int tid = threadIdx.x;
    int blk = blockIdx.x;
    const float* X; const float* W;
    int b, r0, isq;
    if (blk < 64) { isq = 1; b = blk >> 2; r0 = (blk & 3) * 32;
                    X = Q + ((size_t)b * NQ + r0) * DIN; W = Wq; }
    else { blk -= 64; isq = 0; b = blk >> 4; r0 = (blk & 15) * 32;
           X = K + ((size_t)b * NK + r0) * DIN; W = Wk;
           int vl = vlen[b]; vl = vl < 1 ? 1 : (vl > NK ? NK : vl);
           if (r0 >= vl) return;     // block-uniform: masked-out key rows, never read
    }

    {   // stage 32 rows of X: 2048 float4, coalesced
        const float4* Xg = (const float4*)X;
        float4* Xs = (float4*)Xl;
        #pragma unroll
        for (int i = 0; i < 8; ++i) Xs[tid + 256 * i] = Xg[tid + 256 * i];
    }

    const int h4 = tid & 31;          // h = 4*h4
    const int rg = tid >> 5;          // rows rg*4 .. rg*4+3
    const float4* Wg = (const float4*)W;   // [256*128/4] float4; chunk c at c*2048
    float4* Ws4 = (float4*)Wl;

    float4 acc[4];
    #pragma unroll
    for (int r = 0; r < 4; ++r) { acc[r].x = 0.f; acc[r].y = 0.f; acc[r].z = 0.f; acc[r].w = 0.f; }

    // chunk 0: load to regs, write to LDS (first __syncthreads is inside loop)
    float4 pre[8];
    #pragma unroll
    for (int j = 0; j < 8; ++j) pre[j] = Wg[tid + 256 * j];
    #pragma unroll
    for (int j = 0; j < 8; ++j) Ws4[tid + 256 * j] = pre[j];

    for (int c = 0; c < 4; ++c) {     // 4 d-chunks of 64
        if (c < 3) {                  // issue next chunk's loads; latency hides under compute
            #pragma unroll
            for (int j = 0; j < 8; ++j) pre[j] = Wg[(c + 1) * 2048 + tid + 256 * j];
        }
        __syncthreads();              // Wl (and Xl on c==0) ready

        const float* Xc = &Xl[c * 64];
        #pragma unroll 4
        for (int dd = 0; dd < 64; dd += 4) {
            float4 w0 = *(const float4*)&Wl[(dd + 0) * NH + 4 * h4];
            float4 w1 = *(const float4*)&Wl[(dd + 1) * NH + 4 * h4];
            float4 w2 = *(const float4*)&Wl[(dd + 2) * NH + 4 * h4];
            float4 w3 = *(const float4*)&Wl[(dd + 3) * NH + 4 * h4];
            #pragma unroll
            for (int r = 0; r < 4; ++r) {
                float4 x = *(const float4*)&Xc[(rg * 4 + r) * DIN + dd];  // broadcast
                acc[r].x += x.x * w0.x + x.y * w1.x + x.z * w2.x + x.w * w3.x;
                acc[r].y += x.x * w0.y + x.y * w1.y + x.z * w2.y + x.w * w3.y;
                acc[r].z += x.x * w0.z + x.y * w1.z + x.z * w2.z + x.w * w3.z;
                acc[r].w += x.x * w0.w + x.y * w1.w + x.z * w2.w + x.w * w3.w;
            }
        }
        __syncthreads();              // all waves done reading Wl
        if (c < 3) {
            #pragma unroll
            for (int j = 0; j < 8; ++j) Ws4[tid + 256 * j] = pre[j];
        }
    }

    #pragma unroll
    for (int r = 0; r < 4; ++r) {    // scale then exponentiate: store 2^(CSC*proj)
        acc[r].x = __builtin_amdgcn_exp2f(CSC * acc[r].x);
        acc[r].y = __builtin_amdgcn_exp2f(CSC * acc[r].y);
        acc[r].z = __builtin_amdgcn_exp2f(CSC * acc[r].z);
        acc[r].w = __builtin_amdgcn_exp2f(CSC * acc[r].w);
    }

    if (isq) {
        #pragma unroll
        for (int r = 0; r < 4; ++r)
            *(float4*)&EQ[((size_t)b * NQ + r0 + rg * 4 + r) * NH + 4 * h4] = acc[r];
    } else {
        float* T = Xl;                // [128 h][36] padded (36*4B % 16 == 0)
        __syncthreads();
        #pragma unroll
        for (int r = 0; r < 4; ++r) {
            T[(4 * h4 + 0) * 36 + rg * 4 + r] = acc[r].x;
            T[(4 * h4 + 1) * 36 + rg * 4 + r] = acc[r].y;
            T[(4 * h4 + 2) * 36 + rg * 4 + r] = acc[r].z;
            T[(4 * h4 + 3) * 36 + rg * 4 + r] = acc[r].w;
        }
        __syncthreads();
        #pragma unroll
        for (int i = 0; i < 4; ++i) {
            const int idx = tid + 256 * i;        // 0..1023
            const int h = idx >> 3, c8 = idx & 7; // 8 float4 per h row
            float4 v = *(const float4*)&T[h * 36 + c8 * 4];
            *(float4*)&EKT[((size_t)b * NH + h) * NK + r0 + c8 * 4] = v;
        }
    }
}

// Fused scores + masked softmax + attn@V (v2).  Block = (b, 4 q rows), 512
// thr = 8 waves, grid 512; b = blk&15 -> batch pinned to XCD b%8 (EKT[b]+V[b]
// L2-resident). Changes vs v1:
//  (1) h-PAIRED score math: w0/(1+x0)+w1/(1+x1) = (w0*y1+w1*y0)*rcp(y0*y1),
//      y=1+x: 3 VALU + 0.5 trans per element (was 2 VALU + 1 trans) ->
//      score phase flips from trans-bound to VALU-bound (~-25% on the
//      max-vl critical path; frees trans pipe for cross-block overlap).
//      Overflow: y0*y1 <= ~2^60 finite; inf needs |q+k|>31 sigma (never).
//  (2) scores packed sc4[k][4]: attn@V reads all 4 rows via ONE broadcast
//      ds_read_b128 (was 4x b32). Softmax phase pays a tiny 8-way-conflict
//      strided access (8 reads/8 writes per wave) - negligible.
//  (3) attn@V: unroll 8 (256 cy fma in flight covers ~200 cy L2 latency)
//      and k-loop clamped to kn = min(64, vl-kb0) (skip dead tail).
__global__ __launch_bounds__(512) void attn_fused_kernel(
    const float* __restrict__ EQ, const float* __restrict__ EKT,
    const float* __restrict__ wv, const int* __restrict__ vlen,
    const float* __restrict__ V, float* __restrict__ OUT)
{
    __shared__ float eq4[NH * 4];        // 2KB   [h][r] packed for ds_read_b128
    __shared__ float wvl[NH];            // 0.5KB -2*wv
    __shared__ float sc4[NK * 4];        // 8KB   [k][row] scores -> attn
    __shared__ float part[4][4][NDV];    // 16KB  [k-quarter][row][d]
    const int tid = threadIdx.x;
    const int b  = blockIdx.x & 15;      // XCD-local batch
    const int q0 = (blockIdx.x >> 4) * 4;

    {   // stage q-exponentials transposed: eq4[h*4 + r]
        const int r = tid >> 7, h = tid & 127;
        eq4[h * 4 + r] = EQ[((size_t)b * NQ + q0 + r) * NH + h];
    }
    if (tid < NH) wvl[tid] = -2.0f * wv[tid];
    __syncthreads();

    int vl = vlen[b];
    vl = vl < 1 ? 1 : (vl > NK ? NK : vl);

    // ---- scores: score'(r,k) = sum_h wvl[h]/(1 + eq[r][h]*ek[h][k]),
    // h-paired: one rcp per two h. (true score minus sum(wv): softmax-
    // invariant row shift)
    {
        float a0 = 0.f, a1 = 0.f, a2 = 0.f, a3 = 0.f;
        const bool vld = (tid < vl);
        if (vld) {
            const float* kb = EKT + (size_t)b * NH * NK + tid;
            #pragma unroll 4
            for (int h = 0; h < NH; h += 2) {
                float ek0 = kb[(size_t)h * NK];          // coalesced, L2-hot
                float ek1 = kb[(size_t)(h + 1) * NK];
                float4 ea = *(const float4*)&eq4[h * 4];       // LDS broadcast b128
                float4 eb = *(const float4*)&eq4[(h + 1) * 4];
                float w0 = wvl[h], w1 = wvl[h + 1];
                {   // row 0
                    float y0 = __builtin_fmaf(ea.x, ek0, 1.0f);
                    float y1 = __builtin_fmaf(eb.x, ek1, 1.0f);
                    float n  = __builtin_fmaf(w0, y1, w1 * y0);
                    a0 = __builtin_fmaf(n, __builtin_amdgcn_rcpf(y0 * y1), a0);
                }
                {   // row 1
                    float y0 = __builtin_fmaf(ea.y, ek0, 1.0f);
                    float y1 = __builtin_fmaf(eb.y, ek1, 1.0f);
                    float n  = __builtin_fmaf(w0, y1, w1 * y0);
                    a1 = __builtin_fmaf(n, __builtin_amdgcn_rcpf(y0 * y1), a1);
                }
                {   // row 2
                    float y0 = __builtin_fmaf(ea.z, ek0, 1.0f);
                    float y1 = __builtin_fmaf(eb.z, ek1, 1.0f);
                    float n  = __builtin_fmaf(w0, y1, w1 * y0);
                    a2 = __builtin_fmaf(n, __builtin_amdgcn_rcpf(y0 * y1), a2);
                }
                {   // row 3
                    float y0 = __builtin_fmaf(ea.w, ek0, 1.0f);
                    float y1 = __builtin_fmaf(eb.w, ek1, 1.0f);
                    float n  = __builtin_fmaf(w0, y1, w1 * y0);
                    a3 = __builtin_fmaf(n, __builtin_amdgcn_rcpf(y0 * y1), a3);
                }
            }
        }
        float4 sv;
        sv.x = vld ? a0 : -1e6f;
        sv.y = vld ? a1 : -1e6f;
        sv.z = vld ? a2 : -1e6f;
        sv.w = vld ? a3 : -1e6f;
        *(float4*)&sc4[tid * 4] = sv;    // packed [k][row]
    }
    __syncthreads();

    // ---- masked softmax: wave w (0..3) owns row w (strided sc4 access:
    // 8-way bank conflict on 8 reads + 8 writes - negligible phase)
    const int w = tid >> 6, lane = tid & 63;
    if (w < 4) {
        float vals[8];
        float m = -3.0e38f;
        #pragma unroll
        for (int i = 0; i < 8; ++i) { vals[i] = sc4[(lane + 64 * i) * 4 + w]; m = fmaxf(m, vals[i]); }
        #pragma unroll
        for (int off = 32; off; off >>= 1) m = fmaxf(m, __shfl_xor(m, off, 64));
        float s = 0.f;
        #pragma unroll
        for (int i = 0; i < 8; ++i) {
            vals[i] = __builtin_amdgcn_exp2f((vals[i] - m) * 1.4426950408889634f);
            s += vals[i];
        }
        #pragma unroll
        for (int off = 32; off; off >>= 1) s += __shfl_xor(s, off, 64);
        const float invs = 1.0f / s;   // s >= 1
        #pragma unroll
        for (int i = 0; i < 8; ++i) sc4[(lane + 64 * i) * 4 + w] = vals[i] * invs;
    }
    __syncthreads();

    // ---- out partials: wave w covers k in [w*64, w*64+64) for ALL 4 rows
    float4 o[4];
    #pragma unroll
    for (int r = 0; r < 4; ++r) { o[r].x = 0.f; o[r].y = 0.f; o[r].z = 0.f; o[r].w = 0.f; }
    {
        const int kb0 = w * 64;
        if (kb0 < vl) {                  // wave-uniform: skip all-zero-prob slices
            const int kn = (vl - kb0 < 64) ? (vl - kb0) : 64;  // clamp dead tail
            const float* vb = V + (size_t)b * NK * NDV + lane * 4;
            #pragma unroll 8
            for (int kk = 0; kk < kn; ++kk) {
                const int k = kb0 + kk;
                float4 v4 = *(const float4*)(vb + (size_t)k * NDV);   // 1KB/wave coalesced
                float4 p  = *(const float4*)&sc4[k * 4];              // broadcast b128
                o[0].x += p.x * v4.x; o[0].y += p.x * v4.y; o[0].z += p.x * v4.z; o[0].w += p.x * v4.w;
                o[1].x += p.y * v4.x; o[1].y += p.y * v4.y; o[1].z += p.y * v4.z; o[1].w += p.y * v4.w;
                o[2].x += p.z * v4.x; o[2].y += p.z * v4.y; o[2].z += p.z * v4.z; o[2].w += p.z * v4.w;
                o[3].x += p.w * v4.x; o[3].y += p.w * v4.y; o[3].z += p.w * v4.z; o[3].w += p.w * v4.w;
            }
        }
    }
    // stage 1: waves 4-7 write partials
    if (w >= 4) {
        #pragma unroll
        for (int r = 0; r < 4; ++r) *(float4*)&part[w - 4][r][lane * 4] = o[r];
    }
    __syncthreads();
    // stage 2: waves 0-3 pair-combine and write
    if (w < 4) {
        #pragma unroll
        for (int r = 0; r < 4; ++r) {
            float4 t = *(const float4*)&part[w][r][lane * 4];
            o[r].x += t.x; o[r].y += t.y; o[r].z += t.z; o[r].w += t.w;
            *(float4*)&part[w][r][lane * 4] = o[r];
        }
    }
    __syncthreads();
    // stage 3: sum 4 k-quarter partials, store coalesced
    if (tid < 256) {
        const int r = tid >> 6, d4 = tid & 63;
        float4 s = {0.f, 0.f, 0.f, 0.f};
        #pragma unroll
        for (int p = 0; p < 4; ++p) {
            float4 q = *(const float4*)&part[p][r][d4 * 4];
            s.x += q.x; s.y += q.y; s.z += q.z; s.w += q.w;
        }
        *(float4*)&OUT[((size_t)b * NQ + q0 + r) * NDV + d4 * 4] = s;
    }
}

extern "C" void kernel_launch(void* const* d_in, const int* in_sizes, int n_in,
                              void* d_out, int out_size, void* d_ws, size_t ws_size,
                              hipStream_t stream) {
    const float* queries = (const float*)d_in[0];  // [16,128,256] f32
    const float* keys    = (const float*)d_in[1];  // [16,512,256] f32
    const float* values  = (const float*)d_in[2];  // [16,512,256] f32
    const int*   vlen    = (const int*)d_in[3];    // [16] int32
    const float* Wq      = (const float*)d_in[4];  // [256,128] f32
    const float* Wk      = (const float*)d_in[5];  // [256,128] f32
    const float* wv      = (const float*)d_in[6];  // [128] f32
    float* out           = (float*)d_out;          // [16,128,256] f32

    float* eq  = (float*)d_ws;                     // EQ  [16][128][128] = 1MB (2^(CSC*qproj))
    float* ekt = eq + (size_t)NB * NQ * NH;        // EKT [16][128][512] = 4MB (2^(CSC*kproj), transposed)

    proj_both_kernel<<<64 + 256, 256, 0, stream>>>(queries, keys, Wq, Wk, vlen, eq, ekt);
    attn_fused_kernel<<<NB * 32, 512, 0, stream>>>(eq, ekt, wv, vlen, values, out);
}

// Round 6
// 121.460 us; speedup vs baseline: 1.0688x; 1.0313x over previous
//
#include <hip/hip_runtime.h>
#include <hip/hip_bf16.h>

#define NB 16
#define NQ 128
#define NK 512
#define DIN 256   // QS == KS == 256
#define NH 128
#define NDV 256

#define CSC 2.8853900817779268f   // 2*log2(e): tanh(x) = 1 - 2/(1 + 2^(CSC*x))

// Projection v9 = v7 core + XCD-ALIGNED block mapping. v7 mapped K-block
// (b, r0) to blockIdx 64 + b*16 + r0/32 -> XCD (r0/32)%8: EKT[b]'s slices
// were written into ALL EIGHT XCDs' L2s, while attn pins batch b's readers
// to XCD b%8 -> attn's EKT/EQ reads missed local L2 and fell to L3 (~2x
// latency, much lower BW). v9: blockIdx = qs*16 + b (Q) / 64 + s*16 + b (K)
// -> blockIdx % 8 == b % 8 (64, 16s are 0 mod 8): producer XCD == consumer
// XCD; EKT[b]+EQ[b] are local-L2-hot for attn within the iteration.
// (The 256MiB harness fill flushes L3 each iteration, so only this
// within-iteration L2 handoff can help.)
// Body unchanged from v7: all-LDS inner loop, Xl[32][256]=32KB staged once,
// Wl[64][128]=32KB per d-chunk register-prefetched; 64KB LDS -> 2 blocks/CU.
// Outputs EXPONENTIALS: EQ = 2^(CSC*qproj), EKT = 2^(CSC*kproj) transposed.
// K-path blocks fully beyond valid_len exit immediately (never read).
__global__ __launch_bounds__(256) void proj_both_kernel(
    const float* __restrict__ Q, const float* __restrict__ K,
    const float* __restrict__ Wq, const float* __restrict__ Wk,
    const int* __restrict__ vlen,
    float* __restrict__ EQ, float* __restrict__ EKT)
{
    __shared__ float Xl[32 * DIN];   // 32KB; reused as transpose tile for K path
    __shared__ float Wl[64 * NH];    // 32KB; d-chunk of W
    const int tid = threadIdx.x;
    int blk = blockIdx.x;
    const float* X; const float* W;
    int b, r0, isq;
    if (blk < 64) { isq = 1; b = blk & 15; r0 = (blk >> 4) * 32;   // XCD b%8
                    X = Q + ((size_t)b * NQ + r0) * DIN; W = Wq; }
    else { blk -= 64; isq = 0; b = blk & 15; r0 = (blk >> 4) * 32; // XCD b%8
           X = K + ((size_t)b * NK + r0) * DIN; W = Wk;
           int vl = vlen[b]; vl = vl < 1 ? 1 : (vl > NK ? NK : vl);
           if (r0 >= vl) return;     // block-uniform: masked-out key rows, never read
    }

    {   // stage 32 rows of X: 2048 float4, coalesced
        const float4* Xg = (const float4*)X;
        float4* Xs = (float4*)Xl;
        #pragma unroll
        for (int i = 0; i < 8; ++i) Xs[tid + 256 * i] = Xg[tid + 256 * i];
    }

    const int h4 = tid & 31;          // h = 4*h4
    const int rg = tid >> 5;          // rows rg*4 .. rg*4+3
    const float4* Wg = (const float4*)W;   // [256*128/4] float4; chunk c at c*2048
    float4* Ws4 = (float4*)Wl;

    float4 acc[4];
    #pragma unroll
    for (int r = 0; r < 4; ++r) { acc[r].x = 0.f; acc[r].y = 0.f; acc[r].z = 0.f; acc[r].w = 0.f; }

    // chunk 0: load to regs, write to LDS (first __syncthreads is inside loop)
    float4 pre[8];
    #pragma unroll
    for (int j = 0; j < 8; ++j) pre[j] = Wg[tid + 256 * j];
    #pragma unroll
    for (int j = 0; j < 8; ++j) Ws4[tid + 256 * j] = pre[j];

    for (int c = 0; c < 4; ++c) {     // 4 d-chunks of 64
        if (c < 3) {                  // issue next chunk's loads; latency hides under compute
            #pragma unroll
            for (int j = 0; j < 8; ++j) pre[j] = Wg[(c + 1) * 2048 + tid + 256 * j];
        }
        __syncthreads();              // Wl (and Xl on c==0) ready

        const float* Xc = &Xl[c * 64];
        #pragma unroll 4
        for (int dd = 0; dd < 64; dd += 4) {
            float4 w0 = *(const float4*)&Wl[(dd + 0) * NH + 4 * h4];
            float4 w1 = *(const float4*)&Wl[(dd + 1) * NH + 4 * h4];
            float4 w2 = *(const float4*)&Wl[(dd + 2) * NH + 4 * h4];
            float4 w3 = *(const float4*)&Wl[(dd + 3) * NH + 4 * h4];
            #pragma unroll
            for (int r = 0; r < 4; ++r) {
                float4 x = *(const float4*)&Xc[(rg * 4 + r) * DIN + dd];  // broadcast
                acc[r].x += x.x * w0.x + x.y * w1.x + x.z * w2.x + x.w * w3.x;
                acc[r].y += x.x * w0.y + x.y * w1.y + x.z * w2.y + x.w * w3.y;
                acc[r].z += x.x * w0.z + x.y * w1.z + x.z * w2.z + x.w * w3.z;
                acc[r].w += x.x * w0.w + x.y * w1.w + x.z * w2.w + x.w * w3.w;
            }
        }
        __syncthreads();              // all waves done reading Wl
        if (c < 3) {
            #pragma unroll
            for (int j = 0; j < 8; ++j) Ws4[tid + 256 * j] = pre[j];
        }
    }

    #pragma unroll
    for (int r = 0; r < 4; ++r) {    // scale then exponentiate: store 2^(CSC*proj)
        acc[r].x = __builtin_amdgcn_exp2f(CSC * acc[r].x);
        acc[r].y = __builtin_amdgcn_exp2f(CSC * acc[r].y);
        acc[r].z = __builtin_amdgcn_exp2f(CSC * acc[r].z);
        acc[r].w = __builtin_amdgcn_exp2f(CSC * acc[r].w);
    }

    if (isq) {
        #pragma unroll
        for (int r = 0; r < 4; ++r)
            *(float4*)&EQ[((size_t)b * NQ + r0 + rg * 4 + r) * NH + 4 * h4] = acc[r];
    } else {
        float* T = Xl;                // [128 h][36] padded (36*4B % 16 == 0)
        __syncthreads();
        #pragma unroll
        for (int r = 0; r < 4; ++r) {
            T[(4 * h4 + 0) * 36 + rg * 4 + r] = acc[r].x;
            T[(4 * h4 + 1) * 36 + rg * 4 + r] = acc[r].y;
            T[(4 * h4 + 2) * 36 + rg * 4 + r] = acc[r].z;
            T[(4 * h4 + 3) * 36 + rg * 4 + r] = acc[r].w;
        }
        __syncthreads();
        #pragma unroll
        for (int i = 0; i < 4; ++i) {
            const int idx = tid + 256 * i;        // 0..1023
            const int h = idx >> 3, c8 = idx & 7; // 8 float4 per h row
            float4 v = *(const float4*)&T[h * 36 + c8 * 4];
            *(float4*)&EKT[((size_t)b * NH + h) * NK + r0 + c8 * 4] = v;
        }
    }
}

// Fused scores + masked softmax + attn@V (v2, UNCHANGED from R5 for clean
// attribution of the XCD-alignment fix).  Block = (b, 4 q rows), 512 thr =
// 8 waves, grid 512; b = blk&15 -> batch pinned to XCD b%8; with v9-proj the
// EKT[b]/EQ[b] it reads were WRITTEN on that same XCD (local-L2 hit).
//  (1) h-PAIRED score math: w0/(1+x0)+w1/(1+x1) = (w0*y1+w1*y0)*rcp(y0*y1).
//  (2) scores packed sc4[k][4]: attn@V reads 4 rows via one ds_read_b128.
//  (3) attn@V: unroll 8, k-loop clamped to kn = min(64, vl-kb0).
__global__ __launch_bounds__(512) void attn_fused_kernel(
    const float* __restrict__ EQ, const float* __restrict__ EKT,
    const float* __restrict__ wv, const int* __restrict__ vlen,
    const float* __restrict__ V, float* __restrict__ OUT)
{
    __shared__ float eq4[NH * 4];        // 2KB   [h][r] packed for ds_read_b128
    __shared__ float wvl[NH];            // 0.5KB -2*wv
    __shared__ float sc4[NK * 4];        // 8KB   [k][row] scores -> attn
    __shared__ float part[4][4][NDV];    // 16KB  [k-quarter][row][d]
    const int tid = threadIdx.x;
    const int b  = blockIdx.x & 15;      // XCD-local batch
    const int q0 = (blockIdx.x >> 4) * 4;

    {   // stage q-exponentials transposed: eq4[h*4 + r]
        const int r = tid >> 7, h = tid & 127;
        eq4[h * 4 + r] = EQ[((size_t)b * NQ + q0 + r) * NH + h];
    }
    if (tid < NH) wvl[tid] = -2.0f * wv[tid];
    __syncthreads();

    int vl = vlen[b];
    vl = vl < 1 ? 1 : (vl > NK ? NK : vl);

    // ---- scores: score'(r,k) = sum_h wvl[h]/(1 + eq[r][h]*ek[h][k]),
    // h-paired: one rcp per two h. (true score minus sum(wv): softmax-
    // invariant row shift)
    {
        float a0 = 0.f, a1 = 0.f, a2 = 0.f, a3 = 0.f;
        const bool vld = (tid < vl);
        if (vld) {
            const float* kb = EKT + (size_t)b * NH * NK + tid;
            #pragma unroll 4
            for (int h = 0; h < NH; h += 2) {
                float ek0 = kb[(size_t)h * NK];          // coalesced, local-L2-hot
                float ek1 = kb[(size_t)(h + 1) * NK];
                float4 ea = *(const float4*)&eq4[h * 4];       // LDS broadcast b128
                float4 eb = *(const float4*)&eq4[(h + 1) * 4];
                float w0 = wvl[h], w1 = wvl[h + 1];
                {   // row 0
                    float y0 = __builtin_fmaf(ea.x, ek0, 1.0f);
                    float y1 = __builtin_fmaf(eb.x, ek1, 1.0f);
                    float n  = __builtin_fmaf(w0, y1, w1 * y0);
                    a0 = __builtin_fmaf(n, __builtin_amdgcn_rcpf(y0 * y1), a0);
                }
                {   // row 1
                    float y0 = __builtin_fmaf(ea.y, ek0, 1.0f);
                    float y1 = __builtin_fmaf(eb.y, ek1, 1.0f);
                    float n  = __builtin_fmaf(w0, y1, w1 * y0);
                    a1 = __builtin_fmaf(n, __builtin_amdgcn_rcpf(y0 * y1), a1);
                }
                {   // row 2
                    float y0 = __builtin_fmaf(ea.z, ek0, 1.0f);
                    float y1 = __builtin_fmaf(eb.z, ek1, 1.0f);
                    float n  = __builtin_fmaf(w0, y1, w1 * y0);
                    a2 = __builtin_fmaf(n, __builtin_amdgcn_rcpf(y0 * y1), a2);
                }
                {   // row 3
                    float y0 = __builtin_fmaf(ea.w, ek0, 1.0f);
                    float y1 = __builtin_fmaf(eb.w, ek1, 1.0f);
                    float n  = __builtin_fmaf(w0, y1, w1 * y0);
                    a3 = __builtin_fmaf(n, __builtin_amdgcn_rcpf(y0 * y1), a3);
                }
            }
        }
        float4 sv;
        sv.x = vld ? a0 : -1e6f;
        sv.y = vld ? a1 : -1e6f;
        sv.z = vld ? a2 : -1e6f;
        sv.w = vld ? a3 : -1e6f;
        *(float4*)&sc4[tid * 4] = sv;    // packed [k][row]
    }
    __syncthreads();

    // ---- masked softmax: wave w (0..3) owns row w (strided sc4 access:
    // 8-way bank conflict on 8 reads + 8 writes - negligible phase)
    const int w = tid >> 6, lane = tid & 63;
    if (w < 4) {
        float vals[8];
        float m = -3.0e38f;
        #pragma unroll
        for (int i = 0; i < 8; ++i) { vals[i] = sc4[(lane + 64 * i) * 4 + w]; m = fmaxf(m, vals[i]); }
        #pragma unroll
        for (int off = 32; off; off >>= 1) m = fmaxf(m, __shfl_xor(m, off, 64));
        float s = 0.f;
        #pragma unroll
        for (int i = 0; i < 8; ++i) {
            vals[i] = __builtin_amdgcn_exp2f((vals[i] - m) * 1.4426950408889634f);
            s += vals[i];
        }
        #pragma unroll
        for (int off = 32; off; off >>= 1) s += __shfl_xor(s, off, 64);
        const float invs = 1.0f / s;   // s >= 1
        #pragma unroll
        for (int i = 0; i < 8; ++i) sc4[(lane + 64 * i) * 4 + w] = vals[i] * invs;
    }
    __syncthreads();

    // ---- out partials: wave w covers k in [w*64, w*64+64) for ALL 4 rows
    float4 o[4];
    #pragma unroll
    for (int r = 0; r < 4; ++r) { o[r].x = 0.f; o[r].y = 0.f; o[r].z = 0.f; o[r].w = 0.f; }
    {
        const int kb0 = w * 64;
        if (kb0 < vl) {                  // wave-uniform: skip all-zero-prob slices
            const int kn = (vl - kb0 < 64) ? (vl - kb0) : 64;  // clamp dead tail
            const float* vb = V + (size_t)b * NK * NDV + lane * 4;
            #pragma unroll 8
            for (int kk = 0; kk < kn; ++kk) {
                const int k = kb0 + kk;
                float4 v4 = *(const float4*)(vb + (size_t)k * NDV);   // 1KB/wave coalesced
                float4 p  = *(const float4*)&sc4[k * 4];              // broadcast b128
                o[0].x += p.x * v4.x; o[0].y += p.x * v4.y; o[0].z += p.x * v4.z; o[0].w += p.x * v4.w;
                o[1].x += p.y * v4.x; o[1].y += p.y * v4.y; o[1].z += p.y * v4.z; o[1].w += p.y * v4.w;
                o[2].x += p.z * v4.x; o[2].y += p.z * v4.y; o[2].z += p.z * v4.z; o[2].w += p.z * v4.w;
                o[3].x += p.w * v4.x; o[3].y += p.w * v4.y; o[3].z += p.w * v4.z; o[3].w += p.w * v4.w;
            }
        }
    }
    // stage 1: waves 4-7 write partials
    if (w >= 4) {
        #pragma unroll
        for (int r = 0; r < 4; ++r) *(float4*)&part[w - 4][r][lane * 4] = o[r];
    }
    __syncthreads();
    // stage 2: waves 0-3 pair-combine and write
    if (w < 4) {
        #pragma unroll
        for (int r = 0; r < 4; ++r) {
            float4 t = *(const float4*)&part[w][r][lane * 4];
            o[r].x += t.x; o[r].y += t.y; o[r].z += t.z; o[r].w += t.w;
            *(float4*)&part[w][r][lane * 4] = o[r];
        }
    }
    __syncthreads();
    // stage 3: sum 4 k-quarter partials, store coalesced
    if (tid < 256) {
        const int r = tid >> 6, d4 = tid & 63;
        float4 s = {0.f, 0.f, 0.f, 0.f};
        #pragma unroll
        for (int p = 0; p < 4; ++p) {
            float4 q = *(const float4*)&part[p][r][d4 * 4];
            s.x += q.x; s.y += q.y; s.z += q.z; s.w += q.w;
        }
        *(float4*)&OUT[((size_t)b * NQ + q0 + r) * NDV + d4 * 4] = s;
    }
}

extern "C" void kernel_launch(void* const* d_in, const int* in_sizes, int n_in,
                              void* d_out, int out_size, void* d_ws, size_t ws_size,
                              hipStream_t stream) {
    const float* queries = (const float*)d_in[0];  // [16,128,256] f32
    const float* keys    = (const float*)d_in[1];  // [16,512,256] f32
    const float* values  = (const float*)d_in[2];  // [16,512,256] f32
    const int*   vlen    = (const int*)d_in[3];    // [16] int32
    const float* Wq      = (const float*)d_in[4];  // [256,128] f32
    const float* Wk      = (const float*)d_in[5];  // [256,128] f32
    const float* wv      = (const float*)d_in[6];  // [128] f32
    float* out           = (float*)d_out;          // [16,128,256] f32

    float* eq  = (float*)d_ws;                     // EQ  [16][128][128] = 1MB (2^(CSC*qproj))
    float* ekt = eq + (size_t)NB * NQ * NH;        // EKT [16][128][512] = 4MB (2^(CSC*kproj), transposed)

    proj_both_kernel<<<64 + 256, 256, 0, stream>>>(queries, keys, Wq, Wk, vlen, eq, ekt);
    attn_fused_kernel<<<NB * 32, 512, 0, stream>>>(eq, ekt, wv, vlen, values, out);
}

// Round 7
// 120.568 us; speedup vs baseline: 1.0767x; 1.0074x over previous
//
#include <hip/hip_runtime.h>
#include <hip/hip_bf16.h>

#define NB 16
#define NQ 128
#define NK 512
#define DIN 256   // QS == KS == 256
#define NH 128
#define NDV 256

#define CSC 2.8853900817779268f   // 2*log2(e): tanh(x) = 1 - 2/(1 + 2^(CSC*x))

// Projection v9 (UNCHANGED from R6): v7 all-LDS core + XCD-aligned block
// mapping (blockIdx % 16 == b on both Q and K paths -> producer XCD ==
// consumer XCD; EKT[b]+EQ[b] local-L2-hot for attn within the iteration).
// Outputs EXPONENTIALS: EQ = 2^(CSC*qproj), EKT = 2^(CSC*kproj) transposed.
// K-path blocks fully beyond valid_len exit immediately (never read).
__global__ __launch_bounds__(256) void proj_both_kernel(
    const float* __restrict__ Q, const float* __restrict__ K,
    const float* __restrict__ Wq, const float* __restrict__ Wk,
    const int* __restrict__ vlen,
    float* __restrict__ EQ, float* __restrict__ EKT)
{
    __shared__ float Xl[32 * DIN];   // 32KB; reused as transpose tile for K path
    __shared__ float Wl[64 * NH];    // 32KB; d-chunk of W
    const int tid = threadIdx.x;
    int blk = blockIdx.x;
    const float* X; const float* W;
    int b, r0, isq;
    if (blk < 64) { isq = 1; b = blk & 15; r0 = (blk >> 4) * 32;   // XCD b%8
                    X = Q + ((size_t)b * NQ + r0) * DIN; W = Wq; }
    else { blk -= 64; isq = 0; b = blk & 15; r0 = (blk >> 4) * 32; // XCD b%8
           X = K + ((size_t)b * NK + r0) * DIN; W = Wk;
           int vl = vlen[b]; vl = vl < 1 ? 1 : (vl > NK ? NK : vl);
           if (r0 >= vl) return;     // block-uniform: masked-out key rows, never read
    }

    {   // stage 32 rows of X: 2048 float4, coalesced
        const float4* Xg = (const float4*)X;
        float4* Xs = (float4*)Xl;
        #pragma unroll
        for (int i = 0; i < 8; ++i) Xs[tid + 256 * i] = Xg[tid + 256 * i];
    }

    const int h4 = tid & 31;          // h = 4*h4
    const int rg = tid >> 5;          // rows rg*4 .. rg*4+3
    const float4* Wg = (const float4*)W;   // [256*128/4] float4; chunk c at c*2048
    float4* Ws4 = (float4*)Wl;

    float4 acc[4];
    #pragma unroll
    for (int r = 0; r < 4; ++r) { acc[r].x = 0.f; acc[r].y = 0.f; acc[r].z = 0.f; acc[r].w = 0.f; }

    // chunk 0: load to regs, write to LDS (first __syncthreads is inside loop)
    float4 pre[8];
    #pragma unroll
    for (int j = 0; j < 8; ++j) pre[j] = Wg[tid + 256 * j];
    #pragma unroll
    for (int j = 0; j < 8; ++j) Ws4[tid + 256 * j] = pre[j];

    for (int c = 0; c < 4; ++c) {     // 4 d-chunks of 64
        if (c < 3) {                  // issue next chunk's loads; latency hides under compute
            #pragma unroll
            for (int j = 0; j < 8; ++j) pre[j] = Wg[(c + 1) * 2048 + tid + 256 * j];
        }
        __syncthreads();              // Wl (and Xl on c==0) ready

        const float* Xc = &Xl[c * 64];
        #pragma unroll 4
        for (int dd = 0; dd < 64; dd += 4) {
            float4 w0 = *(const float4*)&Wl[(dd + 0) * NH + 4 * h4];
            float4 w1 = *(const float4*)&Wl[(dd + 1) * NH + 4 * h4];
            float4 w2 = *(const float4*)&Wl[(dd + 2) * NH + 4 * h4];
            float4 w3 = *(const float4*)&Wl[(dd + 3) * NH + 4 * h4];
            #pragma unroll
            for (int r = 0; r < 4; ++r) {
                float4 x = *(const float4*)&Xc[(rg * 4 + r) * DIN + dd];  // broadcast
                acc[r].x += x.x * w0.x + x.y * w1.x + x.z * w2.x + x.w * w3.x;
                acc[r].y += x.x * w0.y + x.y * w1.y + x.z * w2.y + x.w * w3.y;
                acc[r].z += x.x * w0.z + x.y * w1.z + x.z * w2.z + x.w * w3.z;
                acc[r].w += x.x * w0.w + x.y * w1.w + x.z * w2.w + x.w * w3.w;
            }
        }
        __syncthreads();              // all waves done reading Wl
        if (c < 3) {
            #pragma unroll
            for (int j = 0; j < 8; ++j) Ws4[tid + 256 * j] = pre[j];
        }
    }

    #pragma unroll
    for (int r = 0; r < 4; ++r) {    // scale then exponentiate: store 2^(CSC*proj)
        acc[r].x = __builtin_amdgcn_exp2f(CSC * acc[r].x);
        acc[r].y = __builtin_amdgcn_exp2f(CSC * acc[r].y);
        acc[r].z = __builtin_amdgcn_exp2f(CSC * acc[r].z);
        acc[r].w = __builtin_amdgcn_exp2f(CSC * acc[r].w);
    }

    if (isq) {
        #pragma unroll
        for (int r = 0; r < 4; ++r)
            *(float4*)&EQ[((size_t)b * NQ + r0 + rg * 4 + r) * NH + 4 * h4] = acc[r];
    } else {
        float* T = Xl;                // [128 h][36] padded (36*4B % 16 == 0)
        __syncthreads();
        #pragma unroll
        for (int r = 0; r < 4; ++r) {
            T[(4 * h4 + 0) * 36 + rg * 4 + r] = acc[r].x;
            T[(4 * h4 + 1) * 36 + rg * 4 + r] = acc[r].y;
            T[(4 * h4 + 2) * 36 + rg * 4 + r] = acc[r].z;
            T[(4 * h4 + 3) * 36 + rg * 4 + r] = acc[r].w;
        }
        __syncthreads();
        #pragma unroll
        for (int i = 0; i < 4; ++i) {
            const int idx = tid + 256 * i;        // 0..1023
            const int h = idx >> 3, c8 = idx & 7; // 8 float4 per h row
            float4 v = *(const float4*)&T[h * 36 + c8 * 4];
            *(float4*)&EKT[((size_t)b * NH + h) * NK + r0 + c8 * 4] = v;
        }
    }
}

// Fused scores + masked softmax + attn@V (v3). THE R7 FIX: R0 counters show
// VGPR_Count=32 -- __launch_bounds__(512) alone made the compiler allocate
// for max occupancy, leaving NO registers to pipeline the score loop's L2
// loads (2 scalar loads/iter x ~200-400cy latency, needs ~16 in flight).
// That register starvation is why halving compute 3x (R1/R4/R5) was null:
// the critical path was serially-exposed load latency, not ALU.
// v3: __launch_bounds__(512, 2) -> 2 waves/EU min = 16 waves/CU = exactly
// our 2 blocks/CU grid; VGPR cap rises 32 -> 128. Score loop unroll 8
// (16 loads/body). V loop (unroll 8) also gains real pipelining now.
// Math identical to v2: h-paired rcp scores, sc4[k][4] packing, clamped
// V-loop, XCD-pinned batch.
__global__ __launch_bounds__(512, 2) void attn_fused_kernel(
    const float* __restrict__ EQ, const float* __restrict__ EKT,
    const float* __restrict__ wv, const int* __restrict__ vlen,
    const float* __restrict__ V, float* __restrict__ OUT)
{
    __shared__ float eq4[NH * 4];        // 2KB   [h][r] packed for ds_read_b128
    __shared__ float wvl[NH];            // 0.5KB -2*wv
    __shared__ float sc4[NK * 4];        // 8KB   [k][row] scores -> attn
    __shared__ float part[4][4][NDV];    // 16KB  [k-quarter][row][d]
    const int tid = threadIdx.x;
    const int b  = blockIdx.x & 15;      // XCD-local batch
    const int q0 = (blockIdx.x >> 4) * 4;

    {   // stage q-exponentials transposed: eq4[h*4 + r]
        const int r = tid >> 7, h = tid & 127;
        eq4[h * 4 + r] = EQ[((size_t)b * NQ + q0 + r) * NH + h];
    }
    if (tid < NH) wvl[tid] = -2.0f * wv[tid];
    __syncthreads();

    int vl = vlen[b];
    vl = vl < 1 ? 1 : (vl > NK ? NK : vl);

    // ---- scores: score'(r,k) = sum_h wvl[h]/(1 + eq[r][h]*ek[h][k]),
    // h-paired: one rcp per two h. (true score minus sum(wv): softmax-
    // invariant row shift)
    {
        float a0 = 0.f, a1 = 0.f, a2 = 0.f, a3 = 0.f;
        const bool vld = (tid < vl);
        if (vld) {
            const float* kb = EKT + (size_t)b * NH * NK + tid;
            #pragma unroll 8
            for (int h = 0; h < NH; h += 2) {
                float ek0 = kb[(size_t)h * NK];          // coalesced, local-L2-hot
                float ek1 = kb[(size_t)(h + 1) * NK];
                float4 ea = *(const float4*)&eq4[h * 4];       // LDS broadcast b128
                float4 eb = *(const float4*)&eq4[(h + 1) * 4];
                float w0 = wvl[h], w1 = wvl[h + 1];
                {   // row 0
                    float y0 = __builtin_fmaf(ea.x, ek0, 1.0f);
                    float y1 = __builtin_fmaf(eb.x, ek1, 1.0f);
                    float n  = __builtin_fmaf(w0, y1, w1 * y0);
                    a0 = __builtin_fmaf(n, __builtin_amdgcn_rcpf(y0 * y1), a0);
                }
                {   // row 1
                    float y0 = __builtin_fmaf(ea.y, ek0, 1.0f);
                    float y1 = __builtin_fmaf(eb.y, ek1, 1.0f);
                    float n  = __builtin_fmaf(w0, y1, w1 * y0);
                    a1 = __builtin_fmaf(n, __builtin_amdgcn_rcpf(y0 * y1), a1);
                }
                {   // row 2
                    float y0 = __builtin_fmaf(ea.z, ek0, 1.0f);
                    float y1 = __builtin_fmaf(eb.z, ek1, 1.0f);
                    float n  = __builtin_fmaf(w0, y1, w1 * y0);
                    a2 = __builtin_fmaf(n, __builtin_amdgcn_rcpf(y0 * y1), a2);
                }
                {   // row 3
                    float y0 = __builtin_fmaf(ea.w, ek0, 1.0f);
                    float y1 = __builtin_fmaf(eb.w, ek1, 1.0f);
                    float n  = __builtin_fmaf(w0, y1, w1 * y0);
                    a3 = __builtin_fmaf(n, __builtin_amdgcn_rcpf(y0 * y1), a3);
                }
            }
        }
        float4 sv;
        sv.x = vld ? a0 : -1e6f;
        sv.y = vld ? a1 : -1e6f;
        sv.z = vld ? a2 : -1e6f;
        sv.w = vld ? a3 : -1e6f;
        *(float4*)&sc4[tid * 4] = sv;    // packed [k][row]
    }
    __syncthreads();

    // ---- masked softmax: wave w (0..3) owns row w (strided sc4 access:
    // 8-way bank conflict on 8 reads + 8 writes - negligible phase)
    const int w = tid >> 6, lane = tid & 63;
    if (w < 4) {
        float vals[8];
        float m = -3.0e38f;
        #pragma unroll
        for (int i = 0; i < 8; ++i) { vals[i] = sc4[(lane + 64 * i) * 4 + w]; m = fmaxf(m, vals[i]); }
        #pragma unroll
        for (int off = 32; off; off >>= 1) m = fmaxf(m, __shfl_xor(m, off, 64));
        float s = 0.f;
        #pragma unroll
        for (int i = 0; i < 8; ++i) {
            vals[i] = __builtin_amdgcn_exp2f((vals[i] - m) * 1.4426950408889634f);
            s += vals[i];
        }
        #pragma unroll
        for (int off = 32; off; off >>= 1) s += __shfl_xor(s, off, 64);
        const float invs = 1.0f / s;   // s >= 1
        #pragma unroll
        for (int i = 0; i < 8; ++i) sc4[(lane + 64 * i) * 4 + w] = vals[i] * invs;
    }
    __syncthreads();

    // ---- out partials: wave w covers k in [w*64, w*64+64) for ALL 4 rows
    float4 o[4];
    #pragma unroll
    for (int r = 0; r < 4; ++r) { o[r].x = 0.f; o[r].y = 0.f; o[r].z = 0.f; o[r].w = 0.f; }
    {
        const int kb0 = w * 64;
        if (kb0 < vl) {                  // wave-uniform: skip all-zero-prob slices
            const int kn = (vl - kb0 < 64) ? (vl - kb0) : 64;  // clamp dead tail
            const float* vb = V + (size_t)b * NK * NDV + lane * 4;
            #pragma unroll 8
            for (int kk = 0; kk < kn; ++kk) {
                const int k = kb0 + kk;
                float4 v4 = *(const float4*)(vb + (size_t)k * NDV);   // 1KB/wave coalesced
                float4 p  = *(const float4*)&sc4[k * 4];              // broadcast b128
                o[0].x += p.x * v4.x; o[0].y += p.x * v4.y; o[0].z += p.x * v4.z; o[0].w += p.x * v4.w;
                o[1].x += p.y * v4.x; o[1].y += p.y * v4.y; o[1].z += p.y * v4.z; o[1].w += p.y * v4.w;
                o[2].x += p.z * v4.x; o[2].y += p.z * v4.y; o[2].z += p.z * v4.z; o[2].w += p.z * v4.w;
                o[3].x += p.w * v4.x; o[3].y += p.w * v4.y; o[3].z += p.w * v4.z; o[3].w += p.w * v4.w;
            }
        }
    }
    // stage 1: waves 4-7 write partials
    if (w >= 4) {
        #pragma unroll
        for (int r = 0; r < 4; ++r) *(float4*)&part[w - 4][r][lane * 4] = o[r];
    }
    __syncthreads();
    // stage 2: waves 0-3 pair-combine and write
    if (w < 4) {
        #pragma unroll
        for (int r = 0; r < 4; ++r) {
            float4 t = *(const float4*)&part[w][r][lane * 4];
            o[r].x += t.x; o[r].y += t.y; o[r].z += t.z; o[r].w += t.w;
            *(float4*)&part[w][r][lane * 4] = o[r];
        }
    }
    __syncthreads();
    // stage 3: sum 4 k-quarter partials, store coalesced
    if (tid < 256) {
        const int r = tid >> 6, d4 = tid & 63;
        float4 s = {0.f, 0.f, 0.f, 0.f};
        #pragma unroll
        for (int p = 0; p < 4; ++p) {
            float4 q = *(const float4*)&part[p][r][d4 * 4];
            s.x += q.x; s.y += q.y; s.z += q.z; s.w += q.w;
        }
        *(float4*)&OUT[((size_t)b * NQ + q0 + r) * NDV + d4 * 4] = s;
    }
}

extern "C" void kernel_launch(void* const* d_in, const int* in_sizes, int n_in,
                              void* d_out, int out_size, void* d_ws, size_t ws_size,
                              hipStream_t stream) {
    const float* queries = (const float*)d_in[0];  // [16,128,256] f32
    const float* keys    = (const float*)d_in[1];  // [16,512,256] f32
    const float* values  = (const float*)d_in[2];  // [16,512,256] f32
    const int*   vlen    = (const int*)d_in[3];    // [16] int32
    const float* Wq      = (const float*)d_in[4];  // [256,128] f32
    const float* Wk      = (const float*)d_in[5];  // [256,128] f32
    const float* wv      = (const float*)d_in[6];  // [128] f32
    float* out           = (float*)d_out;          // [16,128,256] f32

    float* eq  = (float*)d_ws;                     // EQ  [16][128][128] = 1MB (2^(CSC*qproj))
    float* ekt = eq + (size_t)NB * NQ * NH;        // EKT [16][128][512] = 4MB (2^(CSC*kproj), transposed)

    proj_both_kernel<<<64 + 256, 256, 0, stream>>>(queries, keys, Wq, Wk, vlen, eq, ekt);
    attn_fused_kernel<<<NB * 32, 512, 0, stream>>>(eq, ekt, wv, vlen, values, out);
}